// Round 1
// baseline (180.939 us; speedup 1.0000x reference)
//
#include <hip/hip_runtime.h>
#include <hip/hip_bf16.h>

typedef __attribute__((ext_vector_type(8))) short bf16x8;
typedef __attribute__((ext_vector_type(4))) float f32x4;
typedef unsigned short u16;

#define BATCH 12288

__device__ __forceinline__ u16 f2bf(float f){
  __hip_bfloat16 h = __float2bfloat16(f);
  return *reinterpret_cast<u16*>(&h);
}
__device__ __forceinline__ float bf2f(u16 u){
  __hip_bfloat16 h; *reinterpret_cast<u16*>(&h) = u;
  return __bfloat162float(h);
}
__device__ __forceinline__ f32x4 mfma16(bf16x8 a, bf16x8 b, f32x4 c){
  return __builtin_amdgcn_mfma_f32_16x16x32_bf16(a, b, c, 0, 0, 0);
}
__device__ __forceinline__ float softplusf(float v){ return log1pf(expf(v)); }

// ---------------- K0: convert a weight matrix into a zero-padded [128][128] bf16 slab
__global__ __launch_bounds__(256) void k_wconv(const float* __restrict__ src,
                                               u16* __restrict__ dst,
                                               int rows, int cols){
  int idx = blockIdx.x * 256 + threadIdx.x;     // 64 blocks -> 16384
  int r = idx >> 7, c = idx & 127;
  float v = (r < rows && c < cols) ? src[r * cols + c] : 0.f;
  dst[idx] = f2bf(v);
}

// ---------------- K1: 4-layer compression MLP via MFMA (32 rows / block)
__global__ __launch_bounds__(256) void k_mlp(const float* __restrict__ x,
    const u16* __restrict__ slabs,
    const float* __restrict__ cb0, const float* __restrict__ cb1,
    const float* __restrict__ cb2, const float* __restrict__ cb3,
    const float* __restrict__ sb0, const float* __restrict__ sb1,
    const float* __restrict__ sb2, const float* __restrict__ sb3,
    float* __restrict__ comp)
{
  const int LSTR = 136;                       // LDS row stride (bf16 elems)
  __shared__ u16 xbf[32 * 136];
  __shared__ u16 act[2][32 * 136];
  int tid = threadIdx.x;
  int lane = tid & 63, w = tid >> 6;
  int fr = lane & 15, fg = lane >> 4;
  int r0 = blockIdx.x * 32;

  // stage x (f32 -> bf16) into LDS
  #pragma unroll
  for (int i = 0; i < 4; i++){
    int slot = tid + i * 256;                 // 1024 float4 slots = 32 rows * 32
    int row = slot >> 5, c4 = slot & 31;
    float4 v = *reinterpret_cast<const float4*>(&x[(r0 + row) * 128 + c4 * 4]);
    ushort4 pk;
    pk.x = f2bf(v.x); pk.y = f2bf(v.y); pk.z = f2bf(v.z); pk.w = f2bf(v.w);
    *reinterpret_cast<ushort4*>(&xbf[row * LSTR + c4 * 4]) = pk;
  }
  __syncthreads();

  // x A-fragments kept in registers for all skip GEMMs
  bf16x8 xa[2][4];
  #pragma unroll
  for (int mf = 0; mf < 2; mf++)
    #pragma unroll
    for (int kc = 0; kc < 4; kc++)
      xa[mf][kc] = *reinterpret_cast<const bf16x8*>(&xbf[(16*mf + fr) * LSTR + kc*32 + fg*8]);

  const float* cbs[4] = {cb0, cb1, cb2, cb3};
  const float* sbs[4] = {sb0, sb1, sb2, sb3};
  const int douts[4] = {118, 109, 100, 92};

  #pragma unroll
  for (int s = 0; s < 4; s++){
    const u16* aIn  = (s == 0) ? xbf : &act[(s + 1) & 1][0];
    u16*       aOut = &act[s & 1][0];
    const u16* cwS = slabs + (2*s)     * 16384;
    const u16* swS = slabs + (2*s + 1) * 16384;
    const float* cb = cbs[s];
    const float* sb = sbs[s];
    int dout = douts[s];

    bf16x8 af[2][4];
    #pragma unroll
    for (int mf = 0; mf < 2; mf++)
      #pragma unroll
      for (int kc = 0; kc < 4; kc++)
        af[mf][kc] = *reinterpret_cast<const bf16x8*>(&aIn[(16*mf + fr) * LSTR + kc*32 + fg*8]);

    f32x4 ac1[2][2], ac2[2][2];
    #pragma unroll
    for (int mf = 0; mf < 2; mf++)
      #pragma unroll
      for (int nf = 0; nf < 2; nf++){
        ac1[mf][nf] = (f32x4){0.f,0.f,0.f,0.f};
        ac2[mf][nf] = (f32x4){0.f,0.f,0.f,0.f};
      }

    #pragma unroll
    for (int nf = 0; nf < 2; nf++){
      int o = 32*w + 16*nf + fr;              // output col this lane supplies as B-row
      #pragma unroll
      for (int kc = 0; kc < 4; kc++){
        bf16x8 b1 = *reinterpret_cast<const bf16x8*>(&cwS[o * 128 + kc*32 + fg*8]);
        bf16x8 b2 = *reinterpret_cast<const bf16x8*>(&swS[o * 128 + kc*32 + fg*8]);
        ac1[0][nf] = mfma16(af[0][kc], b1, ac1[0][nf]);
        ac1[1][nf] = mfma16(af[1][kc], b1, ac1[1][nf]);
        ac2[0][nf] = mfma16(xa[0][kc], b2, ac2[0][nf]);
        ac2[1][nf] = mfma16(xa[1][kc], b2, ac2[1][nf]);
      }
    }

    #pragma unroll
    for (int nf = 0; nf < 2; nf++){
      int col = 32*w + 16*nf + fr;
      float cbv = (col < dout) ? cb[col] : 0.f;
      float sbv = (col < dout) ? sb[col] : 0.f;
      #pragma unroll
      for (int mf = 0; mf < 2; mf++){
        #pragma unroll
        for (int r = 0; r < 4; r++){
          float t1 = ac1[mf][nf][r] + cbv;
          float g = 0.5f * t1 * (1.f + erff(t1 * 0.70710678118654752f));
          float v = g + 0.1f * (ac2[mf][nf][r] + sbv);
          int row = 16*mf + fg*4 + r;
          if (s < 3){
            aOut[row * LSTR + col] = (col < dout) ? f2bf(v) : (u16)0;
          } else {
            if (col < 92) comp[(r0 + row) * 92 + col] = v;
          }
        }
      }
    }
    __syncthreads();
  }
}

// ---------------- K2a: per-row finalize: bf16 C (padded 96), row norms, energy, basin probs
__global__ __launch_bounds__(256) void k_rowfin(const float* __restrict__ comp,
    u16* __restrict__ Cbf, float* __restrict__ nrm,
    const float* __restrict__ basin_c, const float* __restrict__ basin_d,
    const float* __restrict__ basin_w,
    float* __restrict__ energy_out, float* __restrict__ probs_out)
{
  int tid = threadIdx.x; int lane = tid & 63; int w = tid >> 6;
  int row = blockIdx.x * 4 + w;

  float c0 = comp[row * 92 + lane];
  int d2i = 64 + lane;
  float c1 = (d2i < 92) ? comp[row * 92 + d2i] : 0.f;

  u16 b0 = f2bf(c0);
  u16 b1 = (d2i < 92) ? f2bf(c1) : (u16)0;
  Cbf[row * 96 + lane] = b0;
  if (lane < 32) Cbf[row * 96 + 64 + lane] = b1;   // cols 64..95 (92..95 zero pad)

  // row norm from the *bf16* values (consistency with MFMA gram)
  float f0 = bf2f(b0), f1 = bf2f(b1);
  float ns = f0*f0 + f1*f1;
  #pragma unroll
  for (int m = 1; m < 64; m <<= 1) ns += __shfl_xor(ns, m);
  if (lane == 0) nrm[row] = ns;

  // basin distances (f32 compressed)
  float bd[8];
  #pragma unroll
  for (int b = 0; b < 8; b++){
    float e0 = c0 - basin_c[b * 92 + lane];
    float p = e0 * e0;
    if (d2i < 92){ float e1 = c1 - basin_c[b * 92 + d2i]; p += e1 * e1; }
    #pragma unroll
    for (int m = 1; m < 64; m <<= 1) p += __shfl_xor(p, m);
    bd[b] = sqrtf(p);
  }
  float z[8]; float mx = -1e30f;
  #pragma unroll
  for (int b = 0; b < 8; b++){
    float wd = softplusf(basin_w[b]);
    z[b] = -bd[b] / wd;
    mx = fmaxf(mx, z[b]);
  }
  float p8[8]; float ssum = 0.f;
  #pragma unroll
  for (int b = 0; b < 8; b++){ p8[b] = expf(z[b] - mx); ssum += p8[b]; }
  float inv = 1.f / ssum; float en = 0.f;
  #pragma unroll
  for (int b = 0; b < 8; b++){ p8[b] *= inv; en += p8[b] * basin_d[b]; }

  if (lane == 0) energy_out[row] = en;
  if (lane < 8){
    float v = (lane & 4) ? ((lane & 2) ? ((lane & 1) ? p8[7] : p8[6])
                                       : ((lane & 1) ? p8[5] : p8[4]))
                         : ((lane & 2) ? ((lane & 1) ? p8[3] : p8[2])
                                       : ((lane & 1) ? p8[1] : p8[0]));
    probs_out[row * 8 + lane] = v;
  }
}

// ---------------- K2b: pairwise-distance shell histogram via bf16 MFMA gram
__global__ __launch_bounds__(256) void k_pdist(const u16* __restrict__ Cbf,
    const float* __restrict__ nrm, const float* __restrict__ shell_bnd,
    unsigned* __restrict__ cnt)
{
  __shared__ u16 Bs[2][128 * 104];   // 104-elem stride breaks pow2 bank pathology
  __shared__ float Ns[2][128];
  int tid = threadIdx.x; int lane = tid & 63; int w = tid >> 6;
  int fr = lane & 15, fg = lane >> 4;
  int blk = blockIdx.x;
  int ib = blk % 96, jc = blk / 96;
  int i0 = ib * 128, j0 = jc * 1536;

  float q0 = softplusf(shell_bnd[0]); q0 *= q0;
  float q1 = softplusf(shell_bnd[1]); q1 *= q1;
  float q2 = softplusf(shell_bnd[2]); q2 *= q2;
  float q3 = softplusf(shell_bnd[3]); q3 *= q3;

  int wrow0 = i0 + 32 * w;
  bf16x8 A[2][3];
  #pragma unroll
  for (int mf = 0; mf < 2; mf++)
    #pragma unroll
    for (int kc = 0; kc < 3; kc++)
      A[mf][kc] = *reinterpret_cast<const bf16x8*>(&Cbf[(wrow0 + 16*mf + fr) * 96 + kc*32 + fg*8]);

  float na[2][4];
  #pragma unroll
  for (int mf = 0; mf < 2; mf++)
    #pragma unroll
    for (int r = 0; r < 4; r++)
      na[mf][r] = nrm[wrow0 + 16*mf + fg*4 + r];

  unsigned c[2][4][4];
  #pragma unroll
  for (int mf = 0; mf < 2; mf++)
    #pragma unroll
    for (int r = 0; r < 4; r++)
      #pragma unroll
      for (int t = 0; t < 4; t++) c[mf][r][t] = 0u;

  auto stage = [&](int q, int p){
    int jr0 = j0 + q * 128;
    #pragma unroll
    for (int t = 0; t < 6; t++){
      int ch = tid + t * 256;              // 1536 chunks of 16B
      int rr = ch / 12, sl = ch % 12;
      *reinterpret_cast<bf16x8*>(&Bs[p][rr * 104 + sl * 8]) =
        *reinterpret_cast<const bf16x8*>(&Cbf[(jr0 + rr) * 96 + sl * 8]);
    }
    if (tid < 128) Ns[p][tid] = nrm[jr0 + tid];
  };

  stage(0, 0);
  __syncthreads();

  for (int q = 0; q < 12; q++){
    int p = q & 1;
    if (q < 11) stage(q + 1, p ^ 1);

    for (int nt = 0; nt < 8; nt++){
      bf16x8 B0 = *reinterpret_cast<const bf16x8*>(&Bs[p][(nt*16 + fr) * 104 + 0*32 + fg*8]);
      bf16x8 B1 = *reinterpret_cast<const bf16x8*>(&Bs[p][(nt*16 + fr) * 104 + 1*32 + fg*8]);
      bf16x8 B2 = *reinterpret_cast<const bf16x8*>(&Bs[p][(nt*16 + fr) * 104 + 2*32 + fg*8]);
      float nb = Ns[p][nt*16 + fr];

      f32x4 g0 = (f32x4){0.f,0.f,0.f,0.f};
      f32x4 g1 = (f32x4){0.f,0.f,0.f,0.f};
      g0 = mfma16(A[0][0], B0, g0); g0 = mfma16(A[0][1], B1, g0); g0 = mfma16(A[0][2], B2, g0);
      g1 = mfma16(A[1][0], B0, g1); g1 = mfma16(A[1][1], B1, g1); g1 = mfma16(A[1][2], B2, g1);

      float d2[2][4];
      #pragma unroll
      for (int r = 0; r < 4; r++){
        d2[0][r] = fmaf(-2.f, g0[r], na[0][r] + nb);
        d2[1][r] = fmaf(-2.f, g1[r], na[1][r] + nb);
      }
      float mn = d2[0][0];
      #pragma unroll
      for (int r = 1; r < 4; r++) mn = fminf(mn, d2[0][r]);
      #pragma unroll
      for (int r = 0; r < 4; r++) mn = fminf(mn, d2[1][r]);

      if (__any(mn < q3)){
        #pragma unroll
        for (int mf = 0; mf < 2; mf++)
          #pragma unroll
          for (int r = 0; r < 4; r++){
            float v = d2[mf][r];
            c[mf][r][0] += (v >= q0);
            c[mf][r][1] += (v >= q1);
            c[mf][r][2] += (v >= q2);
            c[mf][r][3] += (v >= q3);
          }
      }
    }
    __syncthreads();
  }

  // reduce over the 16 column-lanes, then shell diffs + atomics
  #pragma unroll
  for (int mf = 0; mf < 2; mf++)
    #pragma unroll
    for (int r = 0; r < 4; r++)
      #pragma unroll
      for (int t = 0; t < 4; t++){
        int v = (int)c[mf][r][t];
        v += __shfl_xor(v, 1); v += __shfl_xor(v, 2);
        v += __shfl_xor(v, 4); v += __shfl_xor(v, 8);
        c[mf][r][t] = (unsigned)v;
      }
  if (fr == 0){
    #pragma unroll
    for (int mf = 0; mf < 2; mf++)
      #pragma unroll
      for (int r = 0; r < 4; r++){
        int row = wrow0 + 16*mf + fg*4 + r;
        #pragma unroll
        for (int s = 0; s < 3; s++){
          unsigned o = c[mf][r][s] - c[mf][r][s + 1];
          if (o) atomicAdd(&cnt[row * 3 + s], o);
        }
      }
  }
}

// ---------------- K3: feats = comp + occ @ se_w^T + se_b ; occ output
__global__ __launch_bounds__(256) void k_feats(const float* __restrict__ comp,
    const unsigned* __restrict__ cnt, const float* __restrict__ se_w,
    const float* __restrict__ se_b, float* __restrict__ feats_out,
    float* __restrict__ occ_out)
{
  int tid = threadIdx.x; int lane = tid & 63; int w = tid >> 6;
  int row = blockIdx.x * 4 + w;
  const float denom = 1.081f * 12287.0f + 1e-8f;

  float o0 = (float)cnt[row * 3 + 0] / denom;
  float o1 = (float)cnt[row * 3 + 1] / denom;
  float o2 = (float)cnt[row * 3 + 2] / denom;

  {
    int d = lane;
    float v = comp[row * 92 + d]
            + o0 * se_w[d * 3 + 0] + o1 * se_w[d * 3 + 1] + o2 * se_w[d * 3 + 2]
            + se_b[d];
    feats_out[row * 92 + d] = v;
  }
  int d2 = lane + 64;
  if (d2 < 92){
    float v = comp[row * 92 + d2]
            + o0 * se_w[d2 * 3 + 0] + o1 * se_w[d2 * 3 + 1] + o2 * se_w[d2 * 3 + 2]
            + se_b[d2];
    feats_out[row * 92 + d2] = v;
  }
  if (lane < 3){
    float ov = (lane == 0) ? o0 : ((lane == 1) ? o1 : o2);
    occ_out[row * 3 + lane] = ov;
  }
}

extern "C" void kernel_launch(void* const* d_in, const int* in_sizes, int n_in,
                              void* d_out, int out_size, void* d_ws, size_t ws_size,
                              hipStream_t stream) {
  (void)in_sizes; (void)n_in; (void)out_size; (void)ws_size;

  const float* x = (const float*)d_in[0];
  const float* cw[4] = {(const float*)d_in[1], (const float*)d_in[5], (const float*)d_in[9],  (const float*)d_in[13]};
  const float* cb[4] = {(const float*)d_in[2], (const float*)d_in[6], (const float*)d_in[10], (const float*)d_in[14]};
  const float* sw[4] = {(const float*)d_in[3], (const float*)d_in[7], (const float*)d_in[11], (const float*)d_in[15]};
  const float* sb[4] = {(const float*)d_in[4], (const float*)d_in[8], (const float*)d_in[12], (const float*)d_in[16]};
  const float* shell_bnd = (const float*)d_in[17];
  const float* se_w = (const float*)d_in[18];
  const float* se_b = (const float*)d_in[19];
  const float* basin_c = (const float*)d_in[20];
  const float* basin_d = (const float*)d_in[21];
  const float* basin_w = (const float*)d_in[22];

  char* ws = (char*)d_ws;
  float*    comp  = (float*)(ws);                    // 12288*92*4   = 4,521,984
  u16*      Cbf   = (u16*)  (ws + 4521984);          // 12288*96*2   = 2,359,296
  float*    nrm   = (float*)(ws + 6881280);          // 12288*4      =    49,152
  unsigned* cnt   = (unsigned*)(ws + 6930432);       // 12288*3*4    =   147,456
  u16*      slabs = (u16*)  (ws + 7077888);          // 8*16384*2    =   262,144

  float* out = (float*)d_out;
  float* feats_out  = out;                 // 12288*92
  float* energy_out = out + 1130496;       // 12288
  float* probs_out  = out + 1142784;       // 12288*8
  float* occ_out    = out + 1241088;       // 12288*3

  hipMemsetAsync(cnt, 0, 147456, stream);

  const int din_c[4] = {128, 118, 109, 100};
  const int dout_[4] = {118, 109, 100, 92};
  for (int s = 0; s < 4; s++){
    k_wconv<<<64, 256, 0, stream>>>(cw[s], slabs + (2*s)     * 16384, dout_[s], din_c[s]);
    k_wconv<<<64, 256, 0, stream>>>(sw[s], slabs + (2*s + 1) * 16384, dout_[s], 128);
  }

  k_mlp<<<384, 256, 0, stream>>>(x, slabs,
      cb[0], cb[1], cb[2], cb[3], sb[0], sb[1], sb[2], sb[3], comp);

  k_rowfin<<<3072, 256, 0, stream>>>(comp, Cbf, nrm, basin_c, basin_d, basin_w,
                                     energy_out, probs_out);

  k_pdist<<<768, 256, 0, stream>>>(Cbf, nrm, shell_bnd, cnt);

  k_feats<<<3072, 256, 0, stream>>>(comp, cnt, se_w, se_b, feats_out, occ_out);
}

// Round 2
// 143.775 us; speedup vs baseline: 1.2585x; 1.2585x over previous
//
#include <hip/hip_runtime.h>
#include <hip/hip_bf16.h>

typedef __attribute__((ext_vector_type(8))) short bf16x8;
typedef __attribute__((ext_vector_type(4))) float f32x4;
typedef unsigned short u16;

#define BATCH 12288

__device__ __forceinline__ u16 f2bf(float f){
  __hip_bfloat16 h = __float2bfloat16(f);
  return *reinterpret_cast<u16*>(&h);
}
__device__ __forceinline__ float bf2f(u16 u){
  __hip_bfloat16 h; *reinterpret_cast<u16*>(&h) = u;
  return __bfloat162float(h);
}
__device__ __forceinline__ f32x4 mfma16(bf16x8 a, bf16x8 b, f32x4 c){
  return __builtin_amdgcn_mfma_f32_16x16x32_bf16(a, b, c, 0, 0, 0);
}
__device__ __forceinline__ float softplusf(float v){ return log1pf(expf(v)); }

// ---------------- K0: all 8 weight matrices -> zero-padded [128][128] bf16 slabs
__global__ __launch_bounds__(256) void k_wconv8(
    const float* __restrict__ s0, const float* __restrict__ s1,
    const float* __restrict__ s2, const float* __restrict__ s3,
    const float* __restrict__ s4, const float* __restrict__ s5,
    const float* __restrict__ s6, const float* __restrict__ s7,
    u16* __restrict__ dst)
{
  int blk = blockIdx.x;            // 512 blocks: 8 slabs x 64
  int slab = blk >> 6;
  const float* src; int rows, cols;
  switch (slab){
    case 0: src = s0; rows = 118; cols = 128; break;
    case 1: src = s1; rows = 118; cols = 128; break;
    case 2: src = s2; rows = 109; cols = 118; break;
    case 3: src = s3; rows = 109; cols = 128; break;
    case 4: src = s4; rows = 100; cols = 109; break;
    case 5: src = s5; rows = 100; cols = 128; break;
    case 6: src = s6; rows =  92; cols = 100; break;
    default: src = s7; rows =  92; cols = 128; break;
  }
  int idx = (blk & 63) * 256 + threadIdx.x;       // 16384 per slab
  int r = idx >> 7, c = idx & 127;
  float v = (r < rows && c < cols) ? src[r * cols + c] : 0.f;
  dst[slab * 16384 + idx] = f2bf(v);
}

// ---------------- K1: 4-layer compression MLP via MFMA (32 rows / block)
__global__ __launch_bounds__(256) void k_mlp(const float* __restrict__ x,
    const u16* __restrict__ slabs,
    const float* __restrict__ cb0, const float* __restrict__ cb1,
    const float* __restrict__ cb2, const float* __restrict__ cb3,
    const float* __restrict__ sb0, const float* __restrict__ sb1,
    const float* __restrict__ sb2, const float* __restrict__ sb3,
    float* __restrict__ comp)
{
  const int LSTR = 136;                       // LDS row stride (bf16 elems)
  __shared__ u16 xbf[32 * 136];
  __shared__ u16 act[2][32 * 136];
  int tid = threadIdx.x;
  int lane = tid & 63, w = tid >> 6;
  int fr = lane & 15, fg = lane >> 4;
  int r0 = blockIdx.x * 32;

  // stage x (f32 -> bf16) into LDS
  #pragma unroll
  for (int i = 0; i < 4; i++){
    int slot = tid + i * 256;                 // 1024 float4 slots = 32 rows * 32
    int row = slot >> 5, c4 = slot & 31;
    float4 v = *reinterpret_cast<const float4*>(&x[(r0 + row) * 128 + c4 * 4]);
    ushort4 pk;
    pk.x = f2bf(v.x); pk.y = f2bf(v.y); pk.z = f2bf(v.z); pk.w = f2bf(v.w);
    *reinterpret_cast<ushort4*>(&xbf[row * LSTR + c4 * 4]) = pk;
  }
  __syncthreads();

  // x A-fragments kept in registers for all skip GEMMs
  bf16x8 xa[2][4];
  #pragma unroll
  for (int mf = 0; mf < 2; mf++)
    #pragma unroll
    for (int kc = 0; kc < 4; kc++)
      xa[mf][kc] = *reinterpret_cast<const bf16x8*>(&xbf[(16*mf + fr) * LSTR + kc*32 + fg*8]);

  const float* cbs[4] = {cb0, cb1, cb2, cb3};
  const float* sbs[4] = {sb0, sb1, sb2, sb3};
  const int douts[4] = {118, 109, 100, 92};

  #pragma unroll
  for (int s = 0; s < 4; s++){
    const u16* aIn  = (s == 0) ? xbf : &act[(s + 1) & 1][0];
    u16*       aOut = &act[s & 1][0];
    const u16* cwS = slabs + (2*s)     * 16384;
    const u16* swS = slabs + (2*s + 1) * 16384;
    const float* cb = cbs[s];
    const float* sb = sbs[s];
    int dout = douts[s];

    bf16x8 af[2][4];
    #pragma unroll
    for (int mf = 0; mf < 2; mf++)
      #pragma unroll
      for (int kc = 0; kc < 4; kc++)
        af[mf][kc] = *reinterpret_cast<const bf16x8*>(&aIn[(16*mf + fr) * LSTR + kc*32 + fg*8]);

    f32x4 ac1[2][2], ac2[2][2];
    #pragma unroll
    for (int mf = 0; mf < 2; mf++)
      #pragma unroll
      for (int nf = 0; nf < 2; nf++){
        ac1[mf][nf] = (f32x4){0.f,0.f,0.f,0.f};
        ac2[mf][nf] = (f32x4){0.f,0.f,0.f,0.f};
      }

    #pragma unroll
    for (int nf = 0; nf < 2; nf++){
      int o = 32*w + 16*nf + fr;              // output col this lane supplies as B-row
      #pragma unroll
      for (int kc = 0; kc < 4; kc++){
        bf16x8 b1 = *reinterpret_cast<const bf16x8*>(&cwS[o * 128 + kc*32 + fg*8]);
        bf16x8 b2 = *reinterpret_cast<const bf16x8*>(&swS[o * 128 + kc*32 + fg*8]);
        ac1[0][nf] = mfma16(af[0][kc], b1, ac1[0][nf]);
        ac1[1][nf] = mfma16(af[1][kc], b1, ac1[1][nf]);
        ac2[0][nf] = mfma16(xa[0][kc], b2, ac2[0][nf]);
        ac2[1][nf] = mfma16(xa[1][kc], b2, ac2[1][nf]);
      }
    }

    #pragma unroll
    for (int nf = 0; nf < 2; nf++){
      int col = 32*w + 16*nf + fr;
      float cbv = (col < dout) ? cb[col] : 0.f;
      float sbv = (col < dout) ? sb[col] : 0.f;
      #pragma unroll
      for (int mf = 0; mf < 2; mf++){
        #pragma unroll
        for (int r = 0; r < 4; r++){
          float t1 = ac1[mf][nf][r] + cbv;
          float g = 0.5f * t1 * (1.f + erff(t1 * 0.70710678118654752f));
          float v = g + 0.1f * (ac2[mf][nf][r] + sbv);
          int row = 16*mf + fg*4 + r;
          if (s < 3){
            aOut[row * LSTR + col] = (col < dout) ? f2bf(v) : (u16)0;
          } else {
            if (col < 92) comp[(r0 + row) * 92 + col] = v;
          }
        }
      }
    }
    __syncthreads();
  }
}

// ---------------- K2a: per-row finalize: bf16 C (padded 96), row norms, energy, basin probs
__global__ __launch_bounds__(256) void k_rowfin(const float* __restrict__ comp,
    u16* __restrict__ Cbf, float* __restrict__ nrm,
    const float* __restrict__ basin_c, const float* __restrict__ basin_d,
    const float* __restrict__ basin_w,
    float* __restrict__ energy_out, float* __restrict__ probs_out)
{
  int tid = threadIdx.x; int lane = tid & 63; int w = tid >> 6;
  int row = blockIdx.x * 4 + w;

  float c0 = comp[row * 92 + lane];
  int d2i = 64 + lane;
  float c1 = (d2i < 92) ? comp[row * 92 + d2i] : 0.f;

  u16 b0 = f2bf(c0);
  u16 b1 = (d2i < 92) ? f2bf(c1) : (u16)0;
  Cbf[row * 96 + lane] = b0;
  if (lane < 32) Cbf[row * 96 + 64 + lane] = b1;   // cols 64..95 (92..95 zero pad)

  // row norm from the *bf16* values (consistency with MFMA gram)
  float f0 = bf2f(b0), f1 = bf2f(b1);
  float ns = f0*f0 + f1*f1;
  #pragma unroll
  for (int m = 1; m < 64; m <<= 1) ns += __shfl_xor(ns, m);
  if (lane == 0) nrm[row] = ns;

  // basin distances (f32 compressed)
  float bd[8];
  #pragma unroll
  for (int b = 0; b < 8; b++){
    float e0 = c0 - basin_c[b * 92 + lane];
    float p = e0 * e0;
    if (d2i < 92){ float e1 = c1 - basin_c[b * 92 + d2i]; p += e1 * e1; }
    #pragma unroll
    for (int m = 1; m < 64; m <<= 1) p += __shfl_xor(p, m);
    bd[b] = sqrtf(p);
  }
  float z[8]; float mx = -1e30f;
  #pragma unroll
  for (int b = 0; b < 8; b++){
    float wd = softplusf(basin_w[b]);
    z[b] = -bd[b] / wd;
    mx = fmaxf(mx, z[b]);
  }
  float p8[8]; float ssum = 0.f;
  #pragma unroll
  for (int b = 0; b < 8; b++){ p8[b] = expf(z[b] - mx); ssum += p8[b]; }
  float inv = 1.f / ssum; float en = 0.f;
  #pragma unroll
  for (int b = 0; b < 8; b++){ p8[b] *= inv; en += p8[b] * basin_d[b]; }

  if (lane == 0) energy_out[row] = en;
  if (lane < 8){
    float v = (lane & 4) ? ((lane & 2) ? ((lane & 1) ? p8[7] : p8[6])
                                       : ((lane & 1) ? p8[5] : p8[4]))
                         : ((lane & 2) ? ((lane & 1) ? p8[3] : p8[2])
                                       : ((lane & 1) ? p8[1] : p8[0]));
    probs_out[row * 8 + lane] = v;
  }
}

// ---------------- K2b: pairwise-distance shell histogram via bf16 MFMA gram
// 256 thr / 4 waves; i-tile 128 rows; j-chunk 384 rows staged 64 at a time
// (double-buffered, 27 KB LDS -> 4 blocks/CU = 16 waves/CU).
__global__ __launch_bounds__(256, 4) void k_pdist(const u16* __restrict__ Cbf,
    const float* __restrict__ nrm, const float* __restrict__ shell_bnd,
    unsigned* __restrict__ cnt)
{
  __shared__ u16 Bs[2][64 * 104];   // 104-elem stride: 13x16B granules, conflict-benign
  __shared__ float Ns[2][64];
  int tid = threadIdx.x; int lane = tid & 63; int w = tid >> 6;
  int fr = lane & 15, fg = lane >> 4;
  int blk = blockIdx.x;
  int ib = blk % 96, jc = blk / 96;         // 96 i-tiles x 32 j-chunks
  int i0 = ib * 128, j0 = jc * 384;

  float q0 = softplusf(shell_bnd[0]); q0 *= q0;
  float q1 = softplusf(shell_bnd[1]); q1 *= q1;
  float q2 = softplusf(shell_bnd[2]); q2 *= q2;
  float q3 = softplusf(shell_bnd[3]); q3 *= q3;

  int wrow0 = i0 + 32 * w;
  bf16x8 A[2][3];
  #pragma unroll
  for (int mf = 0; mf < 2; mf++)
    #pragma unroll
    for (int kc = 0; kc < 3; kc++)
      A[mf][kc] = *reinterpret_cast<const bf16x8*>(&Cbf[(wrow0 + 16*mf + fr) * 96 + kc*32 + fg*8]);

  float na[2][4];
  #pragma unroll
  for (int mf = 0; mf < 2; mf++)
    #pragma unroll
    for (int r = 0; r < 4; r++)
      na[mf][r] = nrm[wrow0 + 16*mf + fg*4 + r];

  unsigned c[2][4][4];
  #pragma unroll
  for (int mf = 0; mf < 2; mf++)
    #pragma unroll
    for (int r = 0; r < 4; r++)
      #pragma unroll
      for (int t = 0; t < 4; t++) c[mf][r][t] = 0u;

  auto stage = [&](int st, int p){
    int jr0 = j0 + st * 64;
    #pragma unroll
    for (int t = 0; t < 3; t++){
      int ch = tid + t * 256;              // 768 chunks of 16B = 64 rows x 12
      int rr = ch / 12, sl = ch - rr * 12;
      *reinterpret_cast<bf16x8*>(&Bs[p][rr * 104 + sl * 8]) =
        *reinterpret_cast<const bf16x8*>(&Cbf[(jr0 + rr) * 96 + sl * 8]);
    }
    if (tid < 64) Ns[p][tid] = nrm[jr0 + tid];
  };

  auto hist = [&](f32x4 h0, f32x4 h1, float nb){
    float d2[2][4];
    #pragma unroll
    for (int r = 0; r < 4; r++){
      d2[0][r] = fmaf(-2.f, h0[r], na[0][r] + nb);
      d2[1][r] = fmaf(-2.f, h1[r], na[1][r] + nb);
    }
    float mn = d2[0][0];
    #pragma unroll
    for (int r = 1; r < 4; r++) mn = fminf(mn, d2[0][r]);
    #pragma unroll
    for (int r = 0; r < 4; r++) mn = fminf(mn, d2[1][r]);
    if (__any(mn < q3)){
      #pragma unroll
      for (int mf = 0; mf < 2; mf++)
        #pragma unroll
        for (int r = 0; r < 4; r++){
          float v = d2[mf][r];
          c[mf][r][0] += (v >= q0);
          c[mf][r][1] += (v >= q1);
          c[mf][r][2] += (v >= q2);
          c[mf][r][3] += (v >= q3);
        }
    }
  };

  stage(0, 0);
  __syncthreads();

  f32x4 gp0, gp1; float nbp = 0.f;
  gp0 = (f32x4){0.f,0.f,0.f,0.f}; gp1 = (f32x4){0.f,0.f,0.f,0.f};

  for (int s = 0; s < 6; s++){
    int p = s & 1;
    if (s < 5) stage(s + 1, p ^ 1);

    #pragma unroll
    for (int nt = 0; nt < 4; nt++){
      bf16x8 B0 = *reinterpret_cast<const bf16x8*>(&Bs[p][(nt*16 + fr) * 104 + 0*32 + fg*8]);
      bf16x8 B1 = *reinterpret_cast<const bf16x8*>(&Bs[p][(nt*16 + fr) * 104 + 1*32 + fg*8]);
      bf16x8 B2 = *reinterpret_cast<const bf16x8*>(&Bs[p][(nt*16 + fr) * 104 + 2*32 + fg*8]);
      float nb = Ns[p][nt*16 + fr];

      f32x4 g0 = (f32x4){0.f,0.f,0.f,0.f};
      f32x4 g1 = (f32x4){0.f,0.f,0.f,0.f};
      g0 = mfma16(A[0][0], B0, g0); g0 = mfma16(A[0][1], B1, g0); g0 = mfma16(A[0][2], B2, g0);
      g1 = mfma16(A[1][0], B0, g1); g1 = mfma16(A[1][1], B1, g1); g1 = mfma16(A[1][2], B2, g1);

      // histogram the PREVIOUS fragment while these MFMAs are in flight
      if (nt > 0 || s > 0) hist(gp0, gp1, nbp);

      gp0 = g0; gp1 = g1; nbp = nb;
    }
    __syncthreads();
  }
  hist(gp0, gp1, nbp);    // drain the pipeline

  // reduce over the 16 column-lanes, then shell diffs + atomics
  #pragma unroll
  for (int mf = 0; mf < 2; mf++)
    #pragma unroll
    for (int r = 0; r < 4; r++)
      #pragma unroll
      for (int t = 0; t < 4; t++){
        int v = (int)c[mf][r][t];
        v += __shfl_xor(v, 1); v += __shfl_xor(v, 2);
        v += __shfl_xor(v, 4); v += __shfl_xor(v, 8);
        c[mf][r][t] = (unsigned)v;
      }
  if (fr == 0){
    #pragma unroll
    for (int mf = 0; mf < 2; mf++)
      #pragma unroll
      for (int r = 0; r < 4; r++){
        int row = wrow0 + 16*mf + fg*4 + r;
        #pragma unroll
        for (int s = 0; s < 3; s++){
          unsigned o = c[mf][r][s] - c[mf][r][s + 1];
          if (o) atomicAdd(&cnt[row * 3 + s], o);
        }
      }
  }
}

// ---------------- K3: feats = comp + occ @ se_w^T + se_b ; occ output
__global__ __launch_bounds__(256) void k_feats(const float* __restrict__ comp,
    const unsigned* __restrict__ cnt, const float* __restrict__ se_w,
    const float* __restrict__ se_b, float* __restrict__ feats_out,
    float* __restrict__ occ_out)
{
  int tid = threadIdx.x; int lane = tid & 63; int w = tid >> 6;
  int row = blockIdx.x * 4 + w;
  const float denom = 1.081f * 12287.0f + 1e-8f;

  float o0 = (float)cnt[row * 3 + 0] / denom;
  float o1 = (float)cnt[row * 3 + 1] / denom;
  float o2 = (float)cnt[row * 3 + 2] / denom;

  {
    int d = lane;
    float v = comp[row * 92 + d]
            + o0 * se_w[d * 3 + 0] + o1 * se_w[d * 3 + 1] + o2 * se_w[d * 3 + 2]
            + se_b[d];
    feats_out[row * 92 + d] = v;
  }
  int d2 = lane + 64;
  if (d2 < 92){
    float v = comp[row * 92 + d2]
            + o0 * se_w[d2 * 3 + 0] + o1 * se_w[d2 * 3 + 1] + o2 * se_w[d2 * 3 + 2]
            + se_b[d2];
    feats_out[row * 92 + d2] = v;
  }
  if (lane < 3){
    float ov = (lane == 0) ? o0 : ((lane == 1) ? o1 : o2);
    occ_out[row * 3 + lane] = ov;
  }
}

extern "C" void kernel_launch(void* const* d_in, const int* in_sizes, int n_in,
                              void* d_out, int out_size, void* d_ws, size_t ws_size,
                              hipStream_t stream) {
  (void)in_sizes; (void)n_in; (void)out_size; (void)ws_size;

  const float* x = (const float*)d_in[0];
  const float* cw[4] = {(const float*)d_in[1], (const float*)d_in[5], (const float*)d_in[9],  (const float*)d_in[13]};
  const float* cb[4] = {(const float*)d_in[2], (const float*)d_in[6], (const float*)d_in[10], (const float*)d_in[14]};
  const float* sw[4] = {(const float*)d_in[3], (const float*)d_in[7], (const float*)d_in[11], (const float*)d_in[15]};
  const float* sb[4] = {(const float*)d_in[4], (const float*)d_in[8], (const float*)d_in[12], (const float*)d_in[16]};
  const float* shell_bnd = (const float*)d_in[17];
  const float* se_w = (const float*)d_in[18];
  const float* se_b = (const float*)d_in[19];
  const float* basin_c = (const float*)d_in[20];
  const float* basin_d = (const float*)d_in[21];
  const float* basin_w = (const float*)d_in[22];

  char* ws = (char*)d_ws;
  float*    comp  = (float*)(ws);                    // 12288*92*4   = 4,521,984
  u16*      Cbf   = (u16*)  (ws + 4521984);          // 12288*96*2   = 2,359,296
  float*    nrm   = (float*)(ws + 6881280);          // 12288*4      =    49,152
  unsigned* cnt   = (unsigned*)(ws + 6930432);       // 12288*3*4    =   147,456
  u16*      slabs = (u16*)  (ws + 7077888);          // 8*16384*2    =   262,144

  float* out = (float*)d_out;
  float* feats_out  = out;                 // 12288*92
  float* energy_out = out + 1130496;       // 12288
  float* probs_out  = out + 1142784;       // 12288*8
  float* occ_out    = out + 1241088;       // 12288*3

  hipMemsetAsync(cnt, 0, 147456, stream);

  k_wconv8<<<512, 256, 0, stream>>>(cw[0], sw[0], cw[1], sw[1], cw[2], sw[2], cw[3], sw[3],
                                    slabs);

  k_mlp<<<384, 256, 0, stream>>>(x, slabs,
      cb[0], cb[1], cb[2], cb[3], sb[0], sb[1], sb[2], sb[3], comp);

  k_rowfin<<<3072, 256, 0, stream>>>(comp, Cbf, nrm, basin_c, basin_d, basin_w,
                                     energy_out, probs_out);

  k_pdist<<<3072, 256, 0, stream>>>(Cbf, nrm, shell_bnd, cnt);

  k_feats<<<3072, 256, 0, stream>>>(comp, cnt, se_w, se_b, feats_out, occ_out);
}